// Round 1
// baseline (710.120 us; speedup 1.0000x reference)
//
#include <hip/hip_runtime.h>
#include <math.h>

// GraphTransformer fused kernel: RMSNorm(q,k) + edge attention + segment softmax.
// Layout facts (from reference): q,k,v:[N,H,C] f32; e:[E,H,C] f32; w_*:[C];
// edge_src:[E] random; edge_dst:[E] SORTED ascending. H=8, C=32 (derived at launch).
//
// Mapping: 1 wave (64 threads) per destination node d.
//   lane tid -> head h = tid>>3, channel quad cq = (tid&7)*4  (float4 per lane)
//   row offset = tid*4 == h*C + cq, so a wave covers one full [H,C]=256-float row.
// Reductions over C=32 (8 lanes) via __shfl_xor 1,2,4.
// Segment range per d found by binary search in sorted edge_dst (wave-uniform).
// Online softmax (m,l running per head, replicated across the 8 lanes of a head).

#define Hh 8
#define Cc 32
#define HC 256
#define EPSf 1e-6f

__global__ __launch_bounds__(64) void gt_attn_kernel(
    const float* __restrict__ q,
    const float* __restrict__ k,
    const float* __restrict__ v,
    const float* __restrict__ e,
    const float* __restrict__ wq,
    const float* __restrict__ wk,
    const int*   __restrict__ edge_src,
    const int*   __restrict__ edge_dst,
    float*       __restrict__ out,
    int N, int E)
{
    const int d   = blockIdx.x;
    const int tid = threadIdx.x;          // 0..63
    const int cq  = (tid & 7) * 4;        // channel-quad base within head

    // ---- segment range [lo, hi) for destination d (edge_dst sorted) ----
    int lo = 0, r = E;
    while (lo < r) { int mid = (lo + r) >> 1; if (edge_dst[mid] < d) lo = mid + 1; else r = mid; }
    int hi = lo; r = E;
    while (hi < r) { int mid = (hi + r) >> 1; if (edge_dst[mid] <= d) hi = mid + 1; else r = mid; }

    const float4 wq4 = *(const float4*)(wq + cq);
    const float4 wk4 = *(const float4*)(wk + cq);

    // ---- qn = RMSNorm(q[d]) * wq ----
    const float4 q4 = *(const float4*)(q + (size_t)d * HC + tid * 4);
    float ss = q4.x*q4.x + q4.y*q4.y + q4.z*q4.z + q4.w*q4.w;
    ss += __shfl_xor(ss, 1); ss += __shfl_xor(ss, 2); ss += __shfl_xor(ss, 4);
    const float qrs = rsqrtf(ss * (1.0f / Cc) + EPSf);
    float4 qn;
    qn.x = q4.x * qrs * wq4.x; qn.y = q4.y * qrs * wq4.y;
    qn.z = q4.z * qrs * wq4.z; qn.w = q4.w * qrs * wq4.w;

    const float qk_scale = rsqrtf((float)Cc);   // 1/sqrt(C)

    // ---- online softmax over this destination's edges ----
    float m = -INFINITY, l = 0.0f;
    float4 acc = make_float4(0.f, 0.f, 0.f, 0.f);

    for (int ei = lo; ei < hi; ++ei) {
        const int src = edge_src[ei];
        const float4 k4 = *(const float4*)(k + (size_t)src * HC + tid * 4);
        // RMSNorm(k[src]) on the fly
        float ks = k4.x*k4.x + k4.y*k4.y + k4.z*k4.z + k4.w*k4.w;
        ks += __shfl_xor(ks, 1); ks += __shfl_xor(ks, 2); ks += __shfl_xor(ks, 4);
        const float krs = rsqrtf(ks * (1.0f / Cc) + EPSf);

        const float4 e4 = *(const float4*)(e + (size_t)ei * HC + tid * 4);
        float4 ke;
        ke.x = k4.x * krs * wk4.x + e4.x;
        ke.y = k4.y * krs * wk4.y + e4.y;
        ke.z = k4.z * krs * wk4.z + e4.z;
        ke.w = k4.w * krs * wk4.w + e4.w;

        float s = qn.x*ke.x + qn.y*ke.y + qn.z*ke.z + qn.w*ke.w;
        s += __shfl_xor(s, 1); s += __shfl_xor(s, 2); s += __shfl_xor(s, 4);
        s *= qk_scale;

        const float m_new = fmaxf(m, s);
        const float alpha = __expf(m - m_new);   // exp(-inf)=0 handles first edge
        const float p     = __expf(s - m_new);
        l = l * alpha + p;

        const float4 v4 = *(const float4*)(v + (size_t)src * HC + tid * 4);
        acc.x = acc.x * alpha + p * (v4.x + e4.x);
        acc.y = acc.y * alpha + p * (v4.y + e4.y);
        acc.z = acc.z * alpha + p * (v4.z + e4.z);
        acc.w = acc.w * alpha + p * (v4.w + e4.w);
        m = m_new;
    }

    float4 o;
    if (l > 0.0f) {
        const float inv = 1.0f / l;
        o.x = acc.x * inv; o.y = acc.y * inv; o.z = acc.z * inv; o.w = acc.w * inv;
    } else {
        o = make_float4(0.f, 0.f, 0.f, 0.f);   // empty destination
    }
    *(float4*)(out + (size_t)d * HC + tid * 4) = o;
}

extern "C" void kernel_launch(void* const* d_in, const int* in_sizes, int n_in,
                              void* d_out, int out_size, void* d_ws, size_t ws_size,
                              hipStream_t stream) {
    const float* q   = (const float*)d_in[0];
    const float* k   = (const float*)d_in[1];
    const float* v   = (const float*)d_in[2];
    const float* e   = (const float*)d_in[3];
    const float* wq  = (const float*)d_in[4];
    const float* wk  = (const float*)d_in[5];
    const int* esrc  = (const int*)d_in[6];
    const int* edst  = (const int*)d_in[7];
    float* out       = (float*)d_out;

    const int E  = in_sizes[6];
    const int hc = in_sizes[3] / E;     // H*C (expect 256)
    const int N  = in_sizes[0] / hc;

    gt_attn_kernel<<<dim3(N), dim3(64), 0, stream>>>(q, k, v, e, wq, wk, esrc, edst, out, N, E);
}

// Round 2
// 706.286 us; speedup vs baseline: 1.0054x; 1.0054x over previous
//
#include <hip/hip_runtime.h>
#include <math.h>

// GraphTransformer fused: RMSNorm(q,k) + edge attention + segment softmax.
// q,k,v:[N,H,C] f32; e:[E,H,C] f32; w_*:[C]; edge_src random; edge_dst SORTED.
// H=8, C=32.
//
// 3 kernels on one stream:
//  1) build_offs:  offs[d] = lower_bound(edge_dst, d), d in [0,N]  (CSR ranges)
//  2) build_kscale: kscale[n,h] = rsqrt(mean(k[n,h,:]^2)+eps)      (k-norm hoist)
//  3) gt_attn_main: 1 wave per dst; lane = head(tid>>3) x chanquad(tid&7);
//     2-edge-unrolled online softmax; all per-edge loads hoisted so the two
//     dot shuffle chains overlap; e streamed nontemporally.

#define Hh 8
#define Cc 32
#define HC 256
#define EPSf 1e-6f

typedef float v4f __attribute__((ext_vector_type(4)));

__global__ __launch_bounds__(256) void build_offs(
    const int* __restrict__ edst, int* __restrict__ offs, int N, int E)
{
    int d = blockIdx.x * 256 + threadIdx.x;
    if (d > N) return;
    int lo = 0, r = E;
    while (lo < r) { int mid = (lo + r) >> 1; if (edst[mid] < d) lo = mid + 1; else r = mid; }
    offs[d] = lo;
}

__global__ __launch_bounds__(256) void build_kscale(
    const float* __restrict__ k, float* __restrict__ kscale, int N)
{
    const int wave = threadIdx.x >> 6, lane = threadIdx.x & 63;
    const int n = blockIdx.x * 4 + wave;
    if (n >= N) return;
    const v4f k4 = *(const v4f*)(k + (size_t)n * HC + lane * 4);
    float ss = k4.x*k4.x + k4.y*k4.y + k4.z*k4.z + k4.w*k4.w;
    ss += __shfl_xor(ss, 1); ss += __shfl_xor(ss, 2); ss += __shfl_xor(ss, 4);
    if ((lane & 7) == 0)
        kscale[n * Hh + (lane >> 3)] = rsqrtf(ss * (1.0f / Cc) + EPSf);
}

__global__ __launch_bounds__(256) void gt_attn_main(
    const float* __restrict__ q,
    const float* __restrict__ k,
    const float* __restrict__ v,
    const float* __restrict__ e,
    const float* __restrict__ wq,
    const float* __restrict__ wk,
    const int*   __restrict__ esrc,
    const int*   __restrict__ offs,
    const float* __restrict__ kscale,
    float*       __restrict__ out,
    int N)
{
    const int wave = threadIdx.x >> 6, lane = threadIdx.x & 63;
    const int d = blockIdx.x * 4 + wave;
    if (d >= N) return;
    const int h  = lane >> 3;
    const int cq = (lane & 7) * 4;

    const int lo = offs[d], hi = offs[d + 1];

    const v4f wq4 = *(const v4f*)(wq + cq);
    const v4f wk4 = *(const v4f*)(wk + cq);

    // qn = RMSNorm(q[d]) * wq
    const v4f q4 = *(const v4f*)(q + (size_t)d * HC + lane * 4);
    float ss = q4.x*q4.x + q4.y*q4.y + q4.z*q4.z + q4.w*q4.w;
    ss += __shfl_xor(ss, 1); ss += __shfl_xor(ss, 2); ss += __shfl_xor(ss, 4);
    const v4f qn = q4 * (rsqrtf(ss * (1.0f / Cc) + EPSf)) * wq4;

    const float qk_scale = rsqrtf((float)Cc);

    float m = -INFINITY, l = 0.0f;
    v4f acc = {0.f, 0.f, 0.f, 0.f};

    int ei = lo;
    for (; ei + 1 < hi; ei += 2) {
        // hoist ALL loads for both edges so latency overlaps both shuffle chains
        const int s0 = esrc[ei], s1 = esrc[ei + 1];
        const v4f ka = *(const v4f*)(k + (size_t)s0 * HC + lane * 4);
        const v4f kb = *(const v4f*)(k + (size_t)s1 * HC + lane * 4);
        const v4f ea = __builtin_nontemporal_load((const v4f*)(e + (size_t)ei * HC + lane * 4));
        const v4f eb = __builtin_nontemporal_load((const v4f*)(e + (size_t)(ei + 1) * HC + lane * 4));
        const v4f va = *(const v4f*)(v + (size_t)s0 * HC + lane * 4);
        const v4f vb = *(const v4f*)(v + (size_t)s1 * HC + lane * 4);
        const float krsa = kscale[s0 * Hh + h];
        const float krsb = kscale[s1 * Hh + h];

        const v4f kea = ka * krsa * wk4 + ea;
        const v4f keb = kb * krsb * wk4 + eb;

        float sa = qn.x*kea.x + qn.y*kea.y + qn.z*kea.z + qn.w*kea.w;
        float sb = qn.x*keb.x + qn.y*keb.y + qn.z*keb.z + qn.w*keb.w;
        sa += __shfl_xor(sa, 1); sb += __shfl_xor(sb, 1);
        sa += __shfl_xor(sa, 2); sb += __shfl_xor(sb, 2);
        sa += __shfl_xor(sa, 4); sb += __shfl_xor(sb, 4);
        sa *= qk_scale; sb *= qk_scale;

        const float mn = fmaxf(m, fmaxf(sa, sb));
        const float al = __expf(m - mn);          // exp(-inf)=0 on first pair
        const float pa = __expf(sa - mn);
        const float pb = __expf(sb - mn);
        l = l * al + pa + pb;
        acc = acc * al + pa * (va + ea) + pb * (vb + eb);
        m = mn;
    }
    if (ei < hi) {
        const int s0 = esrc[ei];
        const v4f ka = *(const v4f*)(k + (size_t)s0 * HC + lane * 4);
        const v4f ea = __builtin_nontemporal_load((const v4f*)(e + (size_t)ei * HC + lane * 4));
        const v4f va = *(const v4f*)(v + (size_t)s0 * HC + lane * 4);
        const float krsa = kscale[s0 * Hh + h];
        const v4f kea = ka * krsa * wk4 + ea;
        float sa = qn.x*kea.x + qn.y*kea.y + qn.z*kea.z + qn.w*kea.w;
        sa += __shfl_xor(sa, 1); sa += __shfl_xor(sa, 2); sa += __shfl_xor(sa, 4);
        sa *= qk_scale;
        const float mn = fmaxf(m, sa);
        const float al = __expf(m - mn);
        const float pa = __expf(sa - mn);
        l = l * al + pa;
        acc = acc * al + pa * (va + ea);
        m = mn;
    }

    v4f o = {0.f, 0.f, 0.f, 0.f};
    if (l > 0.0f) o = acc * (1.0f / l);
    __builtin_nontemporal_store(o, (v4f*)(out + (size_t)d * HC + lane * 4));
}

extern "C" void kernel_launch(void* const* d_in, const int* in_sizes, int n_in,
                              void* d_out, int out_size, void* d_ws, size_t ws_size,
                              hipStream_t stream) {
    const float* q   = (const float*)d_in[0];
    const float* k   = (const float*)d_in[1];
    const float* v   = (const float*)d_in[2];
    const float* e   = (const float*)d_in[3];
    const float* wq  = (const float*)d_in[4];
    const float* wk  = (const float*)d_in[5];
    const int* esrc  = (const int*)d_in[6];
    const int* edst  = (const int*)d_in[7];
    float* out       = (float*)d_out;

    const int E  = in_sizes[6];
    const int hc = in_sizes[3] / E;     // H*C (expect 256)
    const int N  = in_sizes[0] / hc;

    // workspace layout: offs[N+1] ints, then kscale[N*H] floats
    int*   offs   = (int*)d_ws;
    float* kscale = (float*)((char*)d_ws + ((size_t)(N + 1) * sizeof(int) + 255 & ~(size_t)255));

    build_offs  <<<dim3((N + 256) / 256), dim3(256), 0, stream>>>(edst, offs, N, E);
    build_kscale<<<dim3((N + 3) / 4),     dim3(256), 0, stream>>>(k, kscale, N);
    gt_attn_main<<<dim3((N + 3) / 4),     dim3(256), 0, stream>>>(
        q, k, v, e, wq, wk, esrc, offs, kscale, out, N);
}